// Round 8
// baseline (469.020 us; speedup 1.0000x reference)
//
#include <hip/hip_runtime.h>
#include <cstdint>
#include <math.h>

typedef __attribute__((ext_vector_type(8))) short short8;
typedef __attribute__((ext_vector_type(4))) short shortx4;
typedef __attribute__((ext_vector_type(4))) float floatx4;
typedef __attribute__((ext_vector_type(16))) float floatx16;

#define D_MODEL 1024
#define NHEAD   16
#define HDIM    64
#define BATCH   2
#define SEQ     2048
#define MTOT    (BATCH*SEQ)   /* 4096 */

#if __has_builtin(__builtin_amdgcn_exp2f)
#define EXP2(x) __builtin_amdgcn_exp2f(x)
#else
#define EXP2(x) exp2f(x)
#endif

// round-to-nearest-even f32 -> bf16 (bits in a short)
__device__ __forceinline__ short f2bf(float f) {
    union { float f; uint32_t u; } v; v.f = f;
    uint32_t u = v.u;
    uint32_t r = (u + 0x7fffu + ((u >> 16) & 1u)) >> 16;
    return (short)(uint16_t)r;
}

// pack two f32 -> [bf16(lo) | bf16(hi)<<16], round-half-up (1-add-each + v_perm)
__device__ __forceinline__ unsigned pk2(float lo, float hi) {
    union { float f; uint32_t u; } x, y; x.f = lo; y.f = hi;
    return __builtin_amdgcn_perm(y.u + 0x8000u, x.u + 0x8000u, 0x07060302u);
}

// async global->LDS, 16B per lane. LDS dest must be wave-uniform base + lane*16.
__device__ __forceinline__ void async16(const short* g, short* l) {
    __builtin_amdgcn_global_load_lds((__attribute__((address_space(1))) void*)g,
                                     (__attribute__((address_space(3))) void*)l,
                                     16, 0, 0);
}

// ---------------------------------------------------------------- merged cast
__global__ __launch_bounds__(256) void cast_all_kernel(
    const float* __restrict__ x,  const float* __restrict__ Wq, const float* __restrict__ Wk,
    const float* __restrict__ Wv, const float* __restrict__ Wo,
    short* __restrict__ xb, short* __restrict__ wqb, short* __restrict__ wkb,
    short* __restrict__ wvb, short* __restrict__ wob)
{
    const int i = blockIdx.x * 256 + threadIdx.x;   // 8-elem group index
    const float* src; short* dst; int off;
    if (i < 524288) { src = x; dst = xb; off = i; }
    else {
        const int j = i - 524288;
        const int seg = j >> 17, o = j & 131071;
        src = (seg == 0) ? Wq : (seg == 1) ? Wk : (seg == 2) ? Wv : Wo;
        dst = (seg == 0) ? wqb : (seg == 1) ? wkb : (seg == 2) ? wvb : wob;
        off = o;
    }
    const floatx4* p = (const floatx4*)(src + (size_t)off * 8);
    floatx4 a = p[0], b = p[1];
    short8 r;
    r[0]=f2bf(a[0]); r[1]=f2bf(a[1]); r[2]=f2bf(a[2]); r[3]=f2bf(a[3]);
    r[4]=f2bf(b[0]); r[5]=f2bf(b[1]); r[6]=f2bf(b[2]); r[7]=f2bf(b[3]);
    *(short8*)(dst + (size_t)off * 8) = r;
}

// ---------------------------------------------------------------- QKV GEMM
// (unchanged from R7: dbuf + conflict-free coalesced swizzle)
__global__ __launch_bounds__(256, 3) void qkv_gemm_kernel(
    const short* __restrict__ Xb,
    const short* __restrict__ Wqb, const short* __restrict__ Wkb, const short* __restrict__ Wvb,
    const float* __restrict__ bq, const float* __restrict__ bk, const float* __restrict__ bv,
    short* __restrict__ Qo, short* __restrict__ Ko, short* __restrict__ Vo)
{
    const int mode = blockIdx.z;
    const short* W    = (mode == 0) ? Wqb : (mode == 1) ? Wkb : Wvb;
    const float* bias = (mode == 0) ? bq  : (mode == 1) ? bk  : bv;

    const int m_t = blockIdx.y * 128;
    const int n_t = blockIdx.x * 128;
    const int tid = threadIdx.x;
    const int lane = tid & 63, laneM = lane & 15, quad = lane >> 4;
    const int wave = tid >> 6;
    const int wm = (wave >> 1) * 64, wn = (wave & 1) * 64;

    __shared__ short la[2][128][4][8];   // [buf][row][slot][8]
    __shared__ short lb[2][128][4][8];

    floatx4 acc[4][4];
#pragma unroll
    for (int mb = 0; mb < 4; mb++)
#pragma unroll
        for (int nb = 0; nb < 4; nb++) acc[mb][nb] = (floatx4){0.f,0.f,0.f,0.f};

#define QSTAGE(bf, kk)                                                                  \
    {                                                                                   \
        int c = tid;                                                                    \
        async16(Xb + (size_t)(m_t + (c >> 2)) * D_MODEL + (kk) + ((((c & 3) ^ ((c >> 3) & 3))) * 8), \
                &la[bf][0][0][0] + c * 8);                                              \
        c = tid + 256;                                                                  \
        async16(Xb + (size_t)(m_t + (c >> 2)) * D_MODEL + (kk) + ((((c & 3) ^ ((c >> 3) & 3))) * 8), \
                &la[bf][0][0][0] + c * 8);                                              \
        c = tid;                                                                        \
        async16(W  + (size_t)(n_t + (c >> 2)) * D_MODEL + (kk) + ((((c & 3) ^ ((c >> 3) & 3))) * 8), \
                &lb[bf][0][0][0] + c * 8);                                              \
        c = tid + 256;                                                                  \
        async16(W  + (size_t)(n_t + (c >> 2)) * D_MODEL + (kk) + ((((c & 3) ^ ((c >> 3) & 3))) * 8), \
                &lb[bf][0][0][0] + c * 8);                                              \
    }

    QSTAGE(0, 0)

    const int swz = (laneM >> 1) & 3;
    for (int it = 0; it < 32; ++it) {
        const int bf = it & 1;
        __syncthreads();                       // buf[it] ready

        short8 af[4], bfv[4];
#pragma unroll
        for (int mb = 0; mb < 4; mb++) af[mb]  = *(const short8*)&la[bf][wm + mb*16 + laneM][quad ^ swz][0];
#pragma unroll
        for (int nb = 0; nb < 4; nb++) bfv[nb] = *(const short8*)&lb[bf][wn + nb*16 + laneM][quad ^ swz][0];

        if (it < 31) QSTAGE(bf ^ 1, (it + 1) * 32)

#pragma unroll
        for (int mb = 0; mb < 4; mb++)
#pragma unroll
            for (int nb = 0; nb < 4; nb++)
                acc[mb][nb] = __builtin_amdgcn_mfma_f32_16x16x32_bf16(af[mb], bfv[nb], acc[mb][nb], 0, 0, 0);
    }
#undef QSTAGE

    if (mode == 2) {
        // V: store transposed [bh][d][seq], shortx4 along seq
#pragma unroll
        for (int nb = 0; nb < 4; nb++) {
            const int col = n_t + wn + nb*16 + laneM;
            const float bb = bias[col];
            const int h = col >> 6, d = col & 63;
#pragma unroll
            for (int mb = 0; mb < 4; mb++) {
                const int row0 = m_t + wm + mb*16 + quad*4;
                const int bi = row0 >> 11, seq0 = row0 & 2047;
                shortx4 sv;
#pragma unroll
                for (int r = 0; r < 4; r++) sv[r] = f2bf(acc[mb][nb][r] + bb);
                *(shortx4*)(Vo + ((size_t)(bi*NHEAD + h) * HDIM + d) * SEQ + seq0) = sv;
            }
        }
    } else {
        short* out = (mode == 0) ? Qo : Ko;
#pragma unroll
        for (int nb = 0; nb < 4; nb++) {
            const int col = n_t + wn + nb*16 + laneM;
            const float bb = bias[col];
            const int h = col >> 6, d = col & 63;
#pragma unroll
            for (int mb = 0; mb < 4; mb++) {
                const int row0 = m_t + wm + mb*16 + quad*4;
#pragma unroll
                for (int r = 0; r < 4; r++) {
                    float v = acc[mb][nb][r] + bb;
                    v = (mode == 0) ? (2.0f*v - 1.0f) * 0.18033688011112042f  // 0.125*log2(e)
                                    : (2.0f*v - 1.0f);
                    const int m = row0 + r;
                    const int bi = m >> 11, seq = m & 2047;
                    out[((size_t)(bi*NHEAD + h) * SEQ + seq) * HDIM + d] = f2bf(v);
                }
            }
        }
    }
}

// ---------------------------------------------------------------- output GEMM
// (unchanged from R7: 128x64 tile, 512 blocks)
__global__ __launch_bounds__(256, 3) void out_gemm_kernel(
    const short* __restrict__ Ab, const short* __restrict__ Wb,
    const float* __restrict__ bias, float* __restrict__ out)
{
    const int m_t = blockIdx.y * 128;
    const int n_t = blockIdx.x * 64;
    const int tid = threadIdx.x;
    const int lane = tid & 63, laneM = lane & 15, quad = lane >> 4;
    const int wave = tid >> 6;
    const int wm = (wave >> 1) * 64, wn = (wave & 1) * 32;

    __shared__ short la[2][128][4][8];
    __shared__ short lb[2][64][4][8];

    floatx4 acc[4][2];
#pragma unroll
    for (int mb = 0; mb < 4; mb++)
#pragma unroll
        for (int nb = 0; nb < 2; nb++) acc[mb][nb] = (floatx4){0.f,0.f,0.f,0.f};

#define OSTAGE(bf, kk)                                                                  \
    {                                                                                   \
        int c = tid;                                                                    \
        async16(Ab + (size_t)(m_t + (c >> 2)) * D_MODEL + (kk) + ((((c & 3) ^ ((c >> 3) & 3))) * 8), \
                &la[bf][0][0][0] + c * 8);                                              \
        c = tid + 256;                                                                  \
        async16(Ab + (size_t)(m_t + (c >> 2)) * D_MODEL + (kk) + ((((c & 3) ^ ((c >> 3) & 3))) * 8), \
                &la[bf][0][0][0] + c * 8);                                              \
        c = tid;                                                                        \
        async16(Wb + (size_t)(n_t + (c >> 2)) * D_MODEL + (kk) + ((((c & 3) ^ ((c >> 3) & 3))) * 8), \
                &lb[bf][0][0][0] + c * 8);                                              \
    }

    OSTAGE(0, 0)

    const int swz = (laneM >> 1) & 3;
    for (int it = 0; it < 32; ++it) {
        const int bf = it & 1;
        __syncthreads();

        short8 af[4], bfv[2];
#pragma unroll
        for (int mb = 0; mb < 4; mb++) af[mb]  = *(const short8*)&la[bf][wm + mb*16 + laneM][quad ^ swz][0];
#pragma unroll
        for (int nb = 0; nb < 2; nb++) bfv[nb] = *(const short8*)&lb[bf][wn + nb*16 + laneM][quad ^ swz][0];

        if (it < 31) OSTAGE(bf ^ 1, (it + 1) * 32)

#pragma unroll
        for (int mb = 0; mb < 4; mb++)
#pragma unroll
            for (int nb = 0; nb < 2; nb++)
                acc[mb][nb] = __builtin_amdgcn_mfma_f32_16x16x32_bf16(af[mb], bfv[nb], acc[mb][nb], 0, 0, 0);
    }
#undef OSTAGE

#pragma unroll
    for (int nb = 0; nb < 2; nb++) {
        const int col = n_t + wn + nb*16 + laneM;
        const float bb = bias[col];
#pragma unroll
        for (int mb = 0; mb < 4; mb++) {
            const int row0 = m_t + wm + mb*16 + quad*4;
#pragma unroll
            for (int r = 0; r < 4; r++)
                out[(size_t)(row0 + r) * D_MODEL + col] = acc[mb][nb][r] + bb;
        }
    }
}

// ---------------------------------------------------------------- flash attention
// 16 waves (1024 thr): qg = wave&3 picks 32 q-rows, par = wave>>2 in 0..3 picks
// a 64-key lane of each 256-key phase (8 phases). Single-buffered 64 KB staging
// (kt[4]+vtl[4]); residency 2 blocks/CU x 16 waves = 32 waves/CU hides the
// staging drain via TLP (no intra-block dbuf needed at this occupancy).
// Inner math identical to R7. Epilogue: rsum 4->1 merge via 1.5 KB overlay,
// then O 4->2->1 merge reusing the 64 KB staging region.
__global__ __launch_bounds__(1024, 8) void attn_kernel(const short* __restrict__ Qb,
                                                       const short* __restrict__ Kb,
                                                       const short* __restrict__ Vt,
                                                       short* __restrict__ Ob)
{
    const int bh = blockIdx.y;
    const int q0 = blockIdx.x * 128;
    const int tid = threadIdx.x;
    const int wave = tid >> 6, lane = tid & 63;
    const int l31 = lane & 31;
    const bool hi = (lane >> 5) != 0;
    const int qg = wave & 3, par = wave >> 2;

    __shared__ union {
        struct { short kt[4][8][64][8]; short vtl[4][8][64][8]; } s;  // 32 KB + 32 KB
        float mO[2][4][32][64];                                        // 64 KB
        float rsAll[3][128];                                           // 1.5 KB overlay
    } u;

    const short* Kbase = Kb + (size_t)bh * SEQ * HDIM;
    const short* Vbase = Vt + (size_t)bh * HDIM * SEQ;

    // Q fragments (MFMA B operand: B[k=d][n=q], lane n = q)
    const short* Qp = Qb + ((size_t)bh * SEQ + q0 + qg*32 + l31) * HDIM + (hi ? 8 : 0);
    short8 qf[4];
#pragma unroll
    for (int ks = 0; ks < 4; ks++) qf[ks] = *(const short8*)(Qp + ks*16);

    floatx16 o0, o1;
#pragma unroll
    for (int r = 0; r < 16; r++) { o0[r] = 0.f; o1[r] = 0.f; }
    float rsum = 0.f;

    // stage 256 keys (4 parities x 64): K chunk c -> (p=c>>9, oct=(c>>6)&7, key=c&63)
    //                                   V chunk c -> (p=c>>9, oct=(c>>6)&7, d=c&63)
#define STAGE(kk)                                                                          \
    {                                                                                      \
        int c = tid;                                                                       \
        async16(Kbase + (size_t)((kk) + ((c >> 9) << 6) + (c & 63)) * HDIM + (((c >> 6) & 7) * 8), \
                &u.s.kt[0][0][0][0] + c * 8);                                              \
        async16(Vbase + (size_t)(c & 63) * SEQ + (kk) + ((c >> 9) << 6) + (((c >> 6) & 7) * 8), \
                &u.s.vtl[0][0][0][0] + c * 8);                                             \
        c = tid + 1024;                                                                    \
        async16(Kbase + (size_t)((kk) + ((c >> 9) << 6) + (c & 63)) * HDIM + (((c >> 6) & 7) * 8), \
                &u.s.kt[0][0][0][0] + c * 8);                                              \
        async16(Vbase + (size_t)(c & 63) * SEQ + (kk) + ((c >> 9) << 6) + (((c >> 6) & 7) * 8), \
                &u.s.vtl[0][0][0][0] + c * 8);                                             \
    }

    for (int i = 0; i < 8; ++i) {
        STAGE(i * 256)
        __syncthreads();                       // drain: phase buffer ready

        // S^T: D[m=key][n=q]
        floatx16 s0, s1;
#pragma unroll
        for (int r = 0; r < 16; r++) { s0[r] = 0.f; s1[r] = 0.f; }
#pragma unroll
        for (int ks = 0; ks < 4; ks++) {
            const short8 a0 = *(const short8*)&u.s.kt[par][2*ks + hi][l31][0];
            const short8 a1 = *(const short8*)&u.s.kt[par][2*ks + hi][32 + l31][0];
            s0 = __builtin_amdgcn_mfma_f32_32x32x16_bf16(a0, qf[ks], s0, 0, 0, 0);
            s1 = __builtin_amdgcn_mfma_f32_32x32x16_bf16(a1, qf[ks], s1, 0, 0, 0);
        }

        // p = 2^s (raw v_exp_f32), per-lane rsum, pack adjacent-k pairs
        unsigned p[16];
#pragma unroll
        for (int i2 = 0; i2 < 8; i2++) {
            const float a0 = EXP2(s0[2*i2]), b0 = EXP2(s0[2*i2+1]);
            const float a1 = EXP2(s1[2*i2]), b1 = EXP2(s1[2*i2+1]);
            rsum += (a0 + b0) + (a1 + b1);
            p[i2]     = pk2(a0, b0);
            p[8 + i2] = pk2(a1, b1);
        }

        // build A-fragments: one shuffle serves both slots of a (pa,pb) pair
        unsigned fu[4][4];
#pragma unroll
        for (int g = 0; g < 4; g++) {
            const int base = (g >> 1) * 8 + (g & 1) * 4;  // 0,4,8,12
#pragma unroll
            for (int j = 0; j < 2; j++) {
                const unsigned pa = p[base + j], pb = p[base + j + 2];
                const unsigned pre = hi ? pa : pb;
                const unsigned sw = (unsigned)__shfl_xor((int)pre, 32, 64);
                fu[g][j]     = hi ? sw : pa;
                fu[g][j + 2] = hi ? pb : sw;
            }
        }

        // O += P V
#pragma unroll
        for (int ks = 0; ks < 4; ks++) {
            union { unsigned u4[4]; short8 s8; } pf;
            pf.u4[0] = fu[ks][0]; pf.u4[1] = fu[ks][1]; pf.u4[2] = fu[ks][2]; pf.u4[3] = fu[ks][3];
            const short8 v0 = *(const short8*)&u.s.vtl[par][2*ks + hi][l31][0];
            const short8 v1 = *(const short8*)&u.s.vtl[par][2*ks + hi][32 + l31][0];
            o0 = __builtin_amdgcn_mfma_f32_32x32x16_bf16(pf.s8, v0, o0, 0, 0, 0);
            o1 = __builtin_amdgcn_mfma_f32_32x32x16_bf16(pf.s8, v1, o1, 0, 0, 0);
        }

        __syncthreads();                       // all reads done before next STAGE
    }
#undef STAGE

    // own-wave key-half combine: lane l holds sum for q=l31 over this wave's keys
    rsum += __shfl_xor(rsum, 32, 64);

    // ---- rsum 4->1 merge via small overlay (consumed before mO overwrites it)
    if (par >= 1 && !hi) u.rsAll[par - 1][qg*32 + l31] = rsum;
    __syncthreads();
    if (par == 0)
        rsum += u.rsAll[0][qg*32 + l31] + u.rsAll[1][qg*32 + l31] + u.rsAll[2][qg*32 + l31];
    __syncthreads();

    // ---- O merge round A: parities 2,3 deposit
    if (par >= 2) {
        const int sel = par - 2;
#pragma unroll
        for (int r = 0; r < 16; r++) {
            const int qr = (r & 3) + 8 * (r >> 2) + (hi ? 4 : 0);
            u.mO[sel][qg][qr][l31]      = o0[r];
            u.mO[sel][qg][qr][32 + l31] = o1[r];
        }
    }
    __syncthreads();
    if (par < 2) {
#pragma unroll
        for (int r = 0; r < 16; r++) {
            const int qr = (r & 3) + 8 * (r >> 2) + (hi ? 4 : 0);
            o0[r] += u.mO[par][qg][qr][l31];
            o1[r] += u.mO[par][qg][qr][32 + l31];
        }
    }
    __syncthreads();
    // ---- O merge round B: parity 1 deposits
    if (par == 1) {
#pragma unroll
        for (int r = 0; r < 16; r++) {
            const int qr = (r & 3) + 8 * (r >> 2) + (hi ? 4 : 0);
            u.mO[0][qg][qr][l31]      = o0[r];
            u.mO[0][qg][qr][32 + l31] = o1[r];
        }
    }
    __syncthreads();
    if (par == 0) {
        const float inv = 1.0f / rsum;          // lane l: q-row l31
        const int b = bh >> 4, h = bh & 15;
#pragma unroll
        for (int r = 0; r < 16; r++) {
            const int qr = (r & 3) + 8 * (r >> 2) + (hi ? 4 : 0);
            const float invr = __shfl(inv, qr, 64);
            const float v0 = o0[r] + u.mO[0][qg][qr][l31];
            const float v1 = o1[r] + u.mO[0][qg][qr][32 + l31];
            const int seq = q0 + qg*32 + qr;
            short* dst = Ob + ((size_t)(b * SEQ + seq)) * D_MODEL + h * HDIM + l31;
            dst[0]  = f2bf(v0 * invr);
            dst[32] = f2bf(v1 * invr);
        }
    }
}

// ---------------------------------------------------------------- launch
extern "C" void kernel_launch(void* const* d_in, const int* in_sizes, int n_in,
                              void* d_out, int out_size, void* d_ws, size_t ws_size,
                              hipStream_t stream)
{
    const float* x  = (const float*)d_in[0];
    const float* Wq = (const float*)d_in[1];
    const float* bq = (const float*)d_in[2];
    const float* Wk = (const float*)d_in[3];
    const float* bk = (const float*)d_in[4];
    const float* Wv = (const float*)d_in[5];
    const float* bv = (const float*)d_in[6];
    const float* Wo = (const float*)d_in[7];
    const float* bo = (const float*)d_in[8];
    float* out = (float*)d_out;

    short* ws = (short*)d_ws;
    const size_t NX = (size_t)MTOT * D_MODEL;     // 4194304
    const size_t NW = (size_t)D_MODEL * D_MODEL;  // 1048576
    short* xb  = ws;
    short* wqb = xb  + NX;
    short* wkb = wqb + NW;
    short* wvb = wkb + NW;
    short* wob = wvb + NW;
    short* Qb  = wob + NW;
    short* Kb  = Qb  + NX;
    short* Vt  = Kb  + NX;   // V stored transposed directly by qkv_gemm
    short* Ob  = Vt  + NX;

    cast_all_kernel<<<dim3(4096), 256, 0, stream>>>(x, Wq, Wk, Wv, Wo, xb, wqb, wkb, wvb, wob);
    qkv_gemm_kernel<<<dim3(8, 32, 3), 256, 0, stream>>>(xb, wqb, wkb, wvb, bq, bk, bv, Qb, Kb, Vt);
    attn_kernel<<<dim3(16, 32), 1024, 0, stream>>>(Qb, Kb, Vt, Ob);
    out_gemm_kernel<<<dim3(16, 32), 256, 0, stream>>>(Ob, wob, bo, out);
}

// Round 9
// 248.839 us; speedup vs baseline: 1.8848x; 1.8848x over previous
//
#include <hip/hip_runtime.h>
#include <cstdint>
#include <math.h>

typedef __attribute__((ext_vector_type(8))) short short8;
typedef __attribute__((ext_vector_type(4))) short shortx4;
typedef __attribute__((ext_vector_type(4))) float floatx4;
typedef __attribute__((ext_vector_type(16))) float floatx16;

#define D_MODEL 1024
#define NHEAD   16
#define HDIM    64
#define BATCH   2
#define SEQ     2048
#define MTOT    (BATCH*SEQ)   /* 4096 */

#if __has_builtin(__builtin_amdgcn_exp2f)
#define EXP2(x) __builtin_amdgcn_exp2f(x)
#else
#define EXP2(x) exp2f(x)
#endif

// round-to-nearest-even f32 -> bf16 (bits in a short)
__device__ __forceinline__ short f2bf(float f) {
    union { float f; uint32_t u; } v; v.f = f;
    uint32_t u = v.u;
    uint32_t r = (u + 0x7fffu + ((u >> 16) & 1u)) >> 16;
    return (short)(uint16_t)r;
}

// pack two f32 -> [bf16(lo) | bf16(hi)<<16], round-half-up (1-add-each + v_perm)
__device__ __forceinline__ unsigned pk2(float lo, float hi) {
    union { float f; uint32_t u; } x, y; x.f = lo; y.f = hi;
    return __builtin_amdgcn_perm(y.u + 0x8000u, x.u + 0x8000u, 0x07060302u);
}

// async global->LDS, 16B per lane. LDS dest must be wave-uniform base + lane*16.
__device__ __forceinline__ void async16(const short* g, short* l) {
    __builtin_amdgcn_global_load_lds((__attribute__((address_space(1))) void*)g,
                                     (__attribute__((address_space(3))) void*)l,
                                     16, 0, 0);
}

// ---------------------------------------------------------------- merged cast
__global__ __launch_bounds__(256) void cast_all_kernel(
    const float* __restrict__ x,  const float* __restrict__ Wq, const float* __restrict__ Wk,
    const float* __restrict__ Wv, const float* __restrict__ Wo,
    short* __restrict__ xb, short* __restrict__ wqb, short* __restrict__ wkb,
    short* __restrict__ wvb, short* __restrict__ wob)
{
    const int i = blockIdx.x * 256 + threadIdx.x;   // 8-elem group index
    const float* src; short* dst; int off;
    if (i < 524288) { src = x; dst = xb; off = i; }
    else {
        const int j = i - 524288;
        const int seg = j >> 17, o = j & 131071;
        src = (seg == 0) ? Wq : (seg == 1) ? Wk : (seg == 2) ? Wv : Wo;
        dst = (seg == 0) ? wqb : (seg == 1) ? wkb : (seg == 2) ? wvb : wob;
        off = o;
    }
    const floatx4* p = (const floatx4*)(src + (size_t)off * 8);
    floatx4 a = p[0], b = p[1];
    short8 r;
    r[0]=f2bf(a[0]); r[1]=f2bf(a[1]); r[2]=f2bf(a[2]); r[3]=f2bf(a[3]);
    r[4]=f2bf(b[0]); r[5]=f2bf(b[1]); r[6]=f2bf(b[2]); r[7]=f2bf(b[3]);
    *(short8*)(dst + (size_t)off * 8) = r;
}

// ---------------------------------------------------------------- QKV GEMM
// (unchanged from R7: dbuf + conflict-free coalesced swizzle)
__global__ __launch_bounds__(256, 3) void qkv_gemm_kernel(
    const short* __restrict__ Xb,
    const short* __restrict__ Wqb, const short* __restrict__ Wkb, const short* __restrict__ Wvb,
    const float* __restrict__ bq, const float* __restrict__ bk, const float* __restrict__ bv,
    short* __restrict__ Qo, short* __restrict__ Ko, short* __restrict__ Vo)
{
    const int mode = blockIdx.z;
    const short* W    = (mode == 0) ? Wqb : (mode == 1) ? Wkb : Wvb;
    const float* bias = (mode == 0) ? bq  : (mode == 1) ? bk  : bv;

    const int m_t = blockIdx.y * 128;
    const int n_t = blockIdx.x * 128;
    const int tid = threadIdx.x;
    const int lane = tid & 63, laneM = lane & 15, quad = lane >> 4;
    const int wave = tid >> 6;
    const int wm = (wave >> 1) * 64, wn = (wave & 1) * 64;

    __shared__ short la[2][128][4][8];   // [buf][row][slot][8]
    __shared__ short lb[2][128][4][8];

    floatx4 acc[4][4];
#pragma unroll
    for (int mb = 0; mb < 4; mb++)
#pragma unroll
        for (int nb = 0; nb < 4; nb++) acc[mb][nb] = (floatx4){0.f,0.f,0.f,0.f};

#define QSTAGE(bf, kk)                                                                  \
    {                                                                                   \
        int c = tid;                                                                    \
        async16(Xb + (size_t)(m_t + (c >> 2)) * D_MODEL + (kk) + ((((c & 3) ^ ((c >> 3) & 3))) * 8), \
                &la[bf][0][0][0] + c * 8);                                              \
        c = tid + 256;                                                                  \
        async16(Xb + (size_t)(m_t + (c >> 2)) * D_MODEL + (kk) + ((((c & 3) ^ ((c >> 3) & 3))) * 8), \
                &la[bf][0][0][0] + c * 8);                                              \
        c = tid;                                                                        \
        async16(W  + (size_t)(n_t + (c >> 2)) * D_MODEL + (kk) + ((((c & 3) ^ ((c >> 3) & 3))) * 8), \
                &lb[bf][0][0][0] + c * 8);                                              \
        c = tid + 256;                                                                  \
        async16(W  + (size_t)(n_t + (c >> 2)) * D_MODEL + (kk) + ((((c & 3) ^ ((c >> 3) & 3))) * 8), \
                &lb[bf][0][0][0] + c * 8);                                              \
    }

    QSTAGE(0, 0)

    const int swz = (laneM >> 1) & 3;
    for (int it = 0; it < 32; ++it) {
        const int bf = it & 1;
        __syncthreads();                       // buf[it] ready

        short8 af[4], bfv[4];
#pragma unroll
        for (int mb = 0; mb < 4; mb++) af[mb]  = *(const short8*)&la[bf][wm + mb*16 + laneM][quad ^ swz][0];
#pragma unroll
        for (int nb = 0; nb < 4; nb++) bfv[nb] = *(const short8*)&lb[bf][wn + nb*16 + laneM][quad ^ swz][0];

        if (it < 31) QSTAGE(bf ^ 1, (it + 1) * 32)

#pragma unroll
        for (int mb = 0; mb < 4; mb++)
#pragma unroll
            for (int nb = 0; nb < 4; nb++)
                acc[mb][nb] = __builtin_amdgcn_mfma_f32_16x16x32_bf16(af[mb], bfv[nb], acc[mb][nb], 0, 0, 0);
    }
#undef QSTAGE

    if (mode == 2) {
        // V: store transposed [bh][d][seq], shortx4 along seq
#pragma unroll
        for (int nb = 0; nb < 4; nb++) {
            const int col = n_t + wn + nb*16 + laneM;
            const float bb = bias[col];
            const int h = col >> 6, d = col & 63;
#pragma unroll
            for (int mb = 0; mb < 4; mb++) {
                const int row0 = m_t + wm + mb*16 + quad*4;
                const int bi = row0 >> 11, seq0 = row0 & 2047;
                shortx4 sv;
#pragma unroll
                for (int r = 0; r < 4; r++) sv[r] = f2bf(acc[mb][nb][r] + bb);
                *(shortx4*)(Vo + ((size_t)(bi*NHEAD + h) * HDIM + d) * SEQ + seq0) = sv;
            }
        }
    } else {
        short* out = (mode == 0) ? Qo : Ko;
#pragma unroll
        for (int nb = 0; nb < 4; nb++) {
            const int col = n_t + wn + nb*16 + laneM;
            const float bb = bias[col];
            const int h = col >> 6, d = col & 63;
#pragma unroll
            for (int mb = 0; mb < 4; mb++) {
                const int row0 = m_t + wm + mb*16 + quad*4;
#pragma unroll
                for (int r = 0; r < 4; r++) {
                    float v = acc[mb][nb][r] + bb;
                    v = (mode == 0) ? (2.0f*v - 1.0f) * 0.18033688011112042f  // 0.125*log2(e)
                                    : (2.0f*v - 1.0f);
                    const int m = row0 + r;
                    const int bi = m >> 11, seq = m & 2047;
                    out[((size_t)(bi*NHEAD + h) * SEQ + seq) * HDIM + d] = f2bf(v);
                }
            }
        }
    }
}

// ---------------------------------------------------------------- output GEMM
// (unchanged from R7: 128x64 tile, 512 blocks)
__global__ __launch_bounds__(256, 3) void out_gemm_kernel(
    const short* __restrict__ Ab, const short* __restrict__ Wb,
    const float* __restrict__ bias, float* __restrict__ out)
{
    const int m_t = blockIdx.y * 128;
    const int n_t = blockIdx.x * 64;
    const int tid = threadIdx.x;
    const int lane = tid & 63, laneM = lane & 15, quad = lane >> 4;
    const int wave = tid >> 6;
    const int wm = (wave >> 1) * 64, wn = (wave & 1) * 32;

    __shared__ short la[2][128][4][8];
    __shared__ short lb[2][64][4][8];

    floatx4 acc[4][2];
#pragma unroll
    for (int mb = 0; mb < 4; mb++)
#pragma unroll
        for (int nb = 0; nb < 2; nb++) acc[mb][nb] = (floatx4){0.f,0.f,0.f,0.f};

#define OSTAGE(bf, kk)                                                                  \
    {                                                                                   \
        int c = tid;                                                                    \
        async16(Ab + (size_t)(m_t + (c >> 2)) * D_MODEL + (kk) + ((((c & 3) ^ ((c >> 3) & 3))) * 8), \
                &la[bf][0][0][0] + c * 8);                                              \
        c = tid + 256;                                                                  \
        async16(Ab + (size_t)(m_t + (c >> 2)) * D_MODEL + (kk) + ((((c & 3) ^ ((c >> 3) & 3))) * 8), \
                &la[bf][0][0][0] + c * 8);                                              \
        c = tid;                                                                        \
        async16(Wb + (size_t)(n_t + (c >> 2)) * D_MODEL + (kk) + ((((c & 3) ^ ((c >> 3) & 3))) * 8), \
                &lb[bf][0][0][0] + c * 8);                                              \
    }

    OSTAGE(0, 0)

    const int swz = (laneM >> 1) & 3;
    for (int it = 0; it < 32; ++it) {
        const int bf = it & 1;
        __syncthreads();

        short8 af[4], bfv[2];
#pragma unroll
        for (int mb = 0; mb < 4; mb++) af[mb]  = *(const short8*)&la[bf][wm + mb*16 + laneM][quad ^ swz][0];
#pragma unroll
        for (int nb = 0; nb < 2; nb++) bfv[nb] = *(const short8*)&lb[bf][wn + nb*16 + laneM][quad ^ swz][0];

        if (it < 31) OSTAGE(bf ^ 1, (it + 1) * 32)

#pragma unroll
        for (int mb = 0; mb < 4; mb++)
#pragma unroll
            for (int nb = 0; nb < 2; nb++)
                acc[mb][nb] = __builtin_amdgcn_mfma_f32_16x16x32_bf16(af[mb], bfv[nb], acc[mb][nb], 0, 0, 0);
    }
#undef OSTAGE

#pragma unroll
    for (int nb = 0; nb < 2; nb++) {
        const int col = n_t + wn + nb*16 + laneM;
        const float bb = bias[col];
#pragma unroll
        for (int mb = 0; mb < 4; mb++) {
            const int row0 = m_t + wm + mb*16 + quad*4;
#pragma unroll
            for (int r = 0; r < 4; r++)
                out[(size_t)(row0 + r) * D_MODEL + col] = acc[mb][nb][r] + bb;
        }
    }
}

// ---------------------------------------------------------------- flash attention
// 16 waves (1024 thr): qg = wave&3 (32 q-rows each), par = wave>>2 (4-way key
// split, 256 keys/phase, 8 phases). Single-buffered 64 KB staging.
// launch_bounds(1024, 2): budget 256 VGPR -> NO forced spill (R8's (1024,8)
// forced a 64-reg cap, spilled to scratch: VGPR=32, WRITE_SIZE 738 MB, 6x
// regression). Natural allocation is ~56 (R7-measured, identical body); at
// <=64 the HW co-schedules 2 blocks/CU = 32 waves/CU, which is the point.
__global__ __launch_bounds__(1024, 2) void attn_kernel(const short* __restrict__ Qb,
                                                       const short* __restrict__ Kb,
                                                       const short* __restrict__ Vt,
                                                       short* __restrict__ Ob)
{
    const int bh = blockIdx.y;
    const int q0 = blockIdx.x * 128;
    const int tid = threadIdx.x;
    const int wave = tid >> 6, lane = tid & 63;
    const int l31 = lane & 31;
    const bool hi = (lane >> 5) != 0;
    const int qg = wave & 3, par = wave >> 2;

    __shared__ union {
        struct { short kt[4][8][64][8]; short vtl[4][8][64][8]; } s;  // 32 KB + 32 KB
        float mO[2][4][32][64];                                        // 64 KB
        float rsAll[3][128];                                           // 1.5 KB overlay
    } u;

    const short* Kbase = Kb + (size_t)bh * SEQ * HDIM;
    const short* Vbase = Vt + (size_t)bh * HDIM * SEQ;

    // Q fragments (MFMA B operand: B[k=d][n=q], lane n = q)
    const short* Qp = Qb + ((size_t)bh * SEQ + q0 + qg*32 + l31) * HDIM + (hi ? 8 : 0);
    short8 qf[4];
#pragma unroll
    for (int ks = 0; ks < 4; ks++) qf[ks] = *(const short8*)(Qp + ks*16);

    floatx16 o0, o1;
#pragma unroll
    for (int r = 0; r < 16; r++) { o0[r] = 0.f; o1[r] = 0.f; }
    float rsum = 0.f;

    // stage 256 keys (4 parities x 64): K chunk c -> (p=c>>9, oct=(c>>6)&7, key=c&63)
    //                                   V chunk c -> (p=c>>9, oct=(c>>6)&7, d=c&63)
#define STAGE(kk)                                                                          \
    {                                                                                      \
        int c = tid;                                                                       \
        async16(Kbase + (size_t)((kk) + ((c >> 9) << 6) + (c & 63)) * HDIM + (((c >> 6) & 7) * 8), \
                &u.s.kt[0][0][0][0] + c * 8);                                              \
        async16(Vbase + (size_t)(c & 63) * SEQ + (kk) + ((c >> 9) << 6) + (((c >> 6) & 7) * 8), \
                &u.s.vtl[0][0][0][0] + c * 8);                                             \
        c = tid + 1024;                                                                    \
        async16(Kbase + (size_t)((kk) + ((c >> 9) << 6) + (c & 63)) * HDIM + (((c >> 6) & 7) * 8), \
                &u.s.kt[0][0][0][0] + c * 8);                                              \
        async16(Vbase + (size_t)(c & 63) * SEQ + (kk) + ((c >> 9) << 6) + (((c >> 6) & 7) * 8), \
                &u.s.vtl[0][0][0][0] + c * 8);                                             \
    }

    for (int i = 0; i < 8; ++i) {
        STAGE(i * 256)
        __syncthreads();                       // drain: phase buffer ready

        // S^T: D[m=key][n=q]
        floatx16 s0, s1;
#pragma unroll
        for (int r = 0; r < 16; r++) { s0[r] = 0.f; s1[r] = 0.f; }
#pragma unroll
        for (int ks = 0; ks < 4; ks++) {
            const short8 a0 = *(const short8*)&u.s.kt[par][2*ks + hi][l31][0];
            const short8 a1 = *(const short8*)&u.s.kt[par][2*ks + hi][32 + l31][0];
            s0 = __builtin_amdgcn_mfma_f32_32x32x16_bf16(a0, qf[ks], s0, 0, 0, 0);
            s1 = __builtin_amdgcn_mfma_f32_32x32x16_bf16(a1, qf[ks], s1, 0, 0, 0);
        }

        // p = 2^s (raw v_exp_f32), per-lane rsum, pack adjacent-k pairs
        unsigned p[16];
#pragma unroll
        for (int i2 = 0; i2 < 8; i2++) {
            const float a0 = EXP2(s0[2*i2]), b0 = EXP2(s0[2*i2+1]);
            const float a1 = EXP2(s1[2*i2]), b1 = EXP2(s1[2*i2+1]);
            rsum += (a0 + b0) + (a1 + b1);
            p[i2]     = pk2(a0, b0);
            p[8 + i2] = pk2(a1, b1);
        }

        // build A-fragments: one shuffle serves both slots of a (pa,pb) pair
        unsigned fu[4][4];
#pragma unroll
        for (int g = 0; g < 4; g++) {
            const int base = (g >> 1) * 8 + (g & 1) * 4;  // 0,4,8,12
#pragma unroll
            for (int j = 0; j < 2; j++) {
                const unsigned pa = p[base + j], pb = p[base + j + 2];
                const unsigned pre = hi ? pa : pb;
                const unsigned sw = (unsigned)__shfl_xor((int)pre, 32, 64);
                fu[g][j]     = hi ? sw : pa;
                fu[g][j + 2] = hi ? pb : sw;
            }
        }

        // O += P V
#pragma unroll
        for (int ks = 0; ks < 4; ks++) {
            union { unsigned u4[4]; short8 s8; } pf;
            pf.u4[0] = fu[ks][0]; pf.u4[1] = fu[ks][1]; pf.u4[2] = fu[ks][2]; pf.u4[3] = fu[ks][3];
            const short8 v0 = *(const short8*)&u.s.vtl[par][2*ks + hi][l31][0];
            const short8 v1 = *(const short8*)&u.s.vtl[par][2*ks + hi][32 + l31][0];
            o0 = __builtin_amdgcn_mfma_f32_32x32x16_bf16(pf.s8, v0, o0, 0, 0, 0);
            o1 = __builtin_amdgcn_mfma_f32_32x32x16_bf16(pf.s8, v1, o1, 0, 0, 0);
        }

        __syncthreads();                       // all reads done before next STAGE
    }
#undef STAGE

    // own-wave key-half combine: lane l holds sum for q=l31 over this wave's keys
    rsum += __shfl_xor(rsum, 32, 64);

    // ---- rsum 4->1 merge via small overlay (consumed before mO overwrites it)
    if (par >= 1 && !hi) u.rsAll[par - 1][qg*32 + l31] = rsum;
    __syncthreads();
    if (par == 0)
        rsum += u.rsAll[0][qg*32 + l31] + u.rsAll[1][qg*32 + l31] + u.rsAll[2][qg*32 + l31];
    __syncthreads();

    // ---- O merge round A: parities 2,3 deposit
    if (par >= 2) {
        const int sel = par - 2;
#pragma unroll
        for (int r = 0; r < 16; r++) {
            const int qr = (r & 3) + 8 * (r >> 2) + (hi ? 4 : 0);
            u.mO[sel][qg][qr][l31]      = o0[r];
            u.mO[sel][qg][qr][32 + l31] = o1[r];
        }
    }
    __syncthreads();
    if (par < 2) {
#pragma unroll
        for (int r = 0; r < 16; r++) {
            const int qr = (r & 3) + 8 * (r >> 2) + (hi ? 4 : 0);
            o0[r] += u.mO[par][qg][qr][l31];
            o1[r] += u.mO[par][qg][qr][32 + l31];
        }
    }
    __syncthreads();
    // ---- O merge round B: parity 1 deposits
    if (par == 1) {
#pragma unroll
        for (int r = 0; r < 16; r++) {
            const int qr = (r & 3) + 8 * (r >> 2) + (hi ? 4 : 0);
            u.mO[0][qg][qr][l31]      = o0[r];
            u.mO[0][qg][qr][32 + l31] = o1[r];
        }
    }
    __syncthreads();
    if (par == 0) {
        const float inv = 1.0f / rsum;          // lane l: q-row l31
        const int b = bh >> 4, h = bh & 15;
#pragma unroll
        for (int r = 0; r < 16; r++) {
            const int qr = (r & 3) + 8 * (r >> 2) + (hi ? 4 : 0);
            const float invr = __shfl(inv, qr, 64);
            const float v0 = o0[r] + u.mO[0][qg][qr][l31];
            const float v1 = o1[r] + u.mO[0][qg][qr][32 + l31];
            const int seq = q0 + qg*32 + qr;
            short* dst = Ob + ((size_t)(b * SEQ + seq)) * D_MODEL + h * HDIM + l31;
            dst[0]  = f2bf(v0 * invr);
            dst[32] = f2bf(v1 * invr);
        }
    }
}

// ---------------------------------------------------------------- launch
extern "C" void kernel_launch(void* const* d_in, const int* in_sizes, int n_in,
                              void* d_out, int out_size, void* d_ws, size_t ws_size,
                              hipStream_t stream)
{
    const float* x  = (const float*)d_in[0];
    const float* Wq = (const float*)d_in[1];
    const float* bq = (const float*)d_in[2];
    const float* Wk = (const float*)d_in[3];
    const float* bk = (const float*)d_in[4];
    const float* Wv = (const float*)d_in[5];
    const float* bv = (const float*)d_in[6];
    const float* Wo = (const float*)d_in[7];
    const float* bo = (const float*)d_in[8];
    float* out = (float*)d_out;

    short* ws = (short*)d_ws;
    const size_t NX = (size_t)MTOT * D_MODEL;     // 4194304
    const size_t NW = (size_t)D_MODEL * D_MODEL;  // 1048576
    short* xb  = ws;
    short* wqb = xb  + NX;
    short* wkb = wqb + NW;
    short* wvb = wkb + NW;
    short* wob = wvb + NW;
    short* Qb  = wob + NW;
    short* Kb  = Qb  + NX;
    short* Vt  = Kb  + NX;   // V stored transposed directly by qkv_gemm
    short* Ob  = Vt  + NX;

    cast_all_kernel<<<dim3(4096), 256, 0, stream>>>(x, Wq, Wk, Wv, Wo, xb, wqb, wkb, wvb, wob);
    qkv_gemm_kernel<<<dim3(8, 32, 3), 256, 0, stream>>>(xb, wqb, wkb, wvb, bq, bk, bv, Qb, Kb, Vt);
    attn_kernel<<<dim3(16, 32), 1024, 0, stream>>>(Qb, Kb, Vt, Ob);
    out_gemm_kernel<<<dim3(16, 32), 256, 0, stream>>>(Ob, wob, bo, out);
}

// Round 10
// 191.036 us; speedup vs baseline: 2.4551x; 1.3026x over previous
//
#include <hip/hip_runtime.h>
#include <cstdint>
#include <math.h>

typedef __attribute__((ext_vector_type(8))) short short8;
typedef __attribute__((ext_vector_type(4))) short shortx4;
typedef __attribute__((ext_vector_type(4))) float floatx4;
typedef __attribute__((ext_vector_type(16))) float floatx16;

#define D_MODEL 1024
#define NHEAD   16
#define HDIM    64
#define BATCH   2
#define SEQ     2048
#define MTOT    (BATCH*SEQ)   /* 4096 */

#if __has_builtin(__builtin_amdgcn_exp2f)
#define EXP2(x) __builtin_amdgcn_exp2f(x)
#else
#define EXP2(x) exp2f(x)
#endif

// round-to-nearest-even f32 -> bf16 (bits in a short)
__device__ __forceinline__ short f2bf(float f) {
    union { float f; uint32_t u; } v; v.f = f;
    uint32_t u = v.u;
    uint32_t r = (u + 0x7fffu + ((u >> 16) & 1u)) >> 16;
    return (short)(uint16_t)r;
}

// pack two f32 -> [bf16(lo) | bf16(hi)<<16], round-half-up (1-add-each + v_perm)
__device__ __forceinline__ unsigned pk2(float lo, float hi) {
    union { float f; uint32_t u; } x, y; x.f = lo; y.f = hi;
    return __builtin_amdgcn_perm(y.u + 0x8000u, x.u + 0x8000u, 0x07060302u);
}

// async global->LDS, 16B per lane. LDS dest must be wave-uniform base + lane*16.
__device__ __forceinline__ void async16(const short* g, short* l) {
    __builtin_amdgcn_global_load_lds((__attribute__((address_space(1))) void*)g,
                                     (__attribute__((address_space(3))) void*)l,
                                     16, 0, 0);
}

// ---------------------------------------------------------------- merged cast
__global__ __launch_bounds__(256) void cast_all_kernel(
    const float* __restrict__ x,  const float* __restrict__ Wq, const float* __restrict__ Wk,
    const float* __restrict__ Wv, const float* __restrict__ Wo,
    short* __restrict__ xb, short* __restrict__ wqb, short* __restrict__ wkb,
    short* __restrict__ wvb, short* __restrict__ wob)
{
    const int i = blockIdx.x * 256 + threadIdx.x;   // 8-elem group index
    const float* src; short* dst; int off;
    if (i < 524288) { src = x; dst = xb; off = i; }
    else {
        const int j = i - 524288;
        const int seg = j >> 17, o = j & 131071;
        src = (seg == 0) ? Wq : (seg == 1) ? Wk : (seg == 2) ? Wv : Wo;
        dst = (seg == 0) ? wqb : (seg == 1) ? wkb : (seg == 2) ? wvb : wob;
        off = o;
    }
    const floatx4* p = (const floatx4*)(src + (size_t)off * 8);
    floatx4 a = p[0], b = p[1];
    short8 r;
    r[0]=f2bf(a[0]); r[1]=f2bf(a[1]); r[2]=f2bf(a[2]); r[3]=f2bf(a[3]);
    r[4]=f2bf(b[0]); r[5]=f2bf(b[1]); r[6]=f2bf(b[2]); r[7]=f2bf(b[3]);
    *(short8*)(dst + (size_t)off * 8) = r;
}

// ---------------------------------------------------------------- QKV GEMM
// (unchanged from R7: dbuf + conflict-free coalesced swizzle)
__global__ __launch_bounds__(256, 3) void qkv_gemm_kernel(
    const short* __restrict__ Xb,
    const short* __restrict__ Wqb, const short* __restrict__ Wkb, const short* __restrict__ Wvb,
    const float* __restrict__ bq, const float* __restrict__ bk, const float* __restrict__ bv,
    short* __restrict__ Qo, short* __restrict__ Ko, short* __restrict__ Vo)
{
    const int mode = blockIdx.z;
    const short* W    = (mode == 0) ? Wqb : (mode == 1) ? Wkb : Wvb;
    const float* bias = (mode == 0) ? bq  : (mode == 1) ? bk  : bv;

    const int m_t = blockIdx.y * 128;
    const int n_t = blockIdx.x * 128;
    const int tid = threadIdx.x;
    const int lane = tid & 63, laneM = lane & 15, quad = lane >> 4;
    const int wave = tid >> 6;
    const int wm = (wave >> 1) * 64, wn = (wave & 1) * 64;

    __shared__ short la[2][128][4][8];   // [buf][row][slot][8]
    __shared__ short lb[2][128][4][8];

    floatx4 acc[4][4];
#pragma unroll
    for (int mb = 0; mb < 4; mb++)
#pragma unroll
        for (int nb = 0; nb < 4; nb++) acc[mb][nb] = (floatx4){0.f,0.f,0.f,0.f};

#define QSTAGE(bf, kk)                                                                  \
    {                                                                                   \
        int c = tid;                                                                    \
        async16(Xb + (size_t)(m_t + (c >> 2)) * D_MODEL + (kk) + ((((c & 3) ^ ((c >> 3) & 3))) * 8), \
                &la[bf][0][0][0] + c * 8);                                              \
        c = tid + 256;                                                                  \
        async16(Xb + (size_t)(m_t + (c >> 2)) * D_MODEL + (kk) + ((((c & 3) ^ ((c >> 3) & 3))) * 8), \
                &la[bf][0][0][0] + c * 8);                                              \
        c = tid;                                                                        \
        async16(W  + (size_t)(n_t + (c >> 2)) * D_MODEL + (kk) + ((((c & 3) ^ ((c >> 3) & 3))) * 8), \
                &lb[bf][0][0][0] + c * 8);                                              \
        c = tid + 256;                                                                  \
        async16(W  + (size_t)(n_t + (c >> 2)) * D_MODEL + (kk) + ((((c & 3) ^ ((c >> 3) & 3))) * 8), \
                &lb[bf][0][0][0] + c * 8);                                              \
    }

    QSTAGE(0, 0)

    const int swz = (laneM >> 1) & 3;
    for (int it = 0; it < 32; ++it) {
        const int bf = it & 1;
        __syncthreads();                       // buf[it] ready

        short8 af[4], bfv[4];
#pragma unroll
        for (int mb = 0; mb < 4; mb++) af[mb]  = *(const short8*)&la[bf][wm + mb*16 + laneM][quad ^ swz][0];
#pragma unroll
        for (int nb = 0; nb < 4; nb++) bfv[nb] = *(const short8*)&lb[bf][wn + nb*16 + laneM][quad ^ swz][0];

        if (it < 31) QSTAGE(bf ^ 1, (it + 1) * 32)

#pragma unroll
        for (int mb = 0; mb < 4; mb++)
#pragma unroll
            for (int nb = 0; nb < 4; nb++)
                acc[mb][nb] = __builtin_amdgcn_mfma_f32_16x16x32_bf16(af[mb], bfv[nb], acc[mb][nb], 0, 0, 0);
    }
#undef QSTAGE

    if (mode == 2) {
        // V: store transposed [bh][d][seq], shortx4 along seq
#pragma unroll
        for (int nb = 0; nb < 4; nb++) {
            const int col = n_t + wn + nb*16 + laneM;
            const float bb = bias[col];
            const int h = col >> 6, d = col & 63;
#pragma unroll
            for (int mb = 0; mb < 4; mb++) {
                const int row0 = m_t + wm + mb*16 + quad*4;
                const int bi = row0 >> 11, seq0 = row0 & 2047;
                shortx4 sv;
#pragma unroll
                for (int r = 0; r < 4; r++) sv[r] = f2bf(acc[mb][nb][r] + bb);
                *(shortx4*)(Vo + ((size_t)(bi*NHEAD + h) * HDIM + d) * SEQ + seq0) = sv;
            }
        }
    } else {
        short* out = (mode == 0) ? Qo : Ko;
#pragma unroll
        for (int nb = 0; nb < 4; nb++) {
            const int col = n_t + wn + nb*16 + laneM;
            const float bb = bias[col];
            const int h = col >> 6, d = col & 63;
#pragma unroll
            for (int mb = 0; mb < 4; mb++) {
                const int row0 = m_t + wm + mb*16 + quad*4;
#pragma unroll
                for (int r = 0; r < 4; r++) {
                    float v = acc[mb][nb][r] + bb;
                    v = (mode == 0) ? (2.0f*v - 1.0f) * 0.18033688011112042f  // 0.125*log2(e)
                                    : (2.0f*v - 1.0f);
                    const int m = row0 + r;
                    const int bi = m >> 11, seq = m & 2047;
                    out[((size_t)(bi*NHEAD + h) * SEQ + seq) * HDIM + d] = f2bf(v);
                }
            }
        }
    }
}

// ---------------------------------------------------------------- output GEMM
// (unchanged from R7: 128x64 tile, 512 blocks)
__global__ __launch_bounds__(256, 3) void out_gemm_kernel(
    const short* __restrict__ Ab, const short* __restrict__ Wb,
    const float* __restrict__ bias, float* __restrict__ out)
{
    const int m_t = blockIdx.y * 128;
    const int n_t = blockIdx.x * 64;
    const int tid = threadIdx.x;
    const int lane = tid & 63, laneM = lane & 15, quad = lane >> 4;
    const int wave = tid >> 6;
    const int wm = (wave >> 1) * 64, wn = (wave & 1) * 32;

    __shared__ short la[2][128][4][8];
    __shared__ short lb[2][64][4][8];

    floatx4 acc[4][2];
#pragma unroll
    for (int mb = 0; mb < 4; mb++)
#pragma unroll
        for (int nb = 0; nb < 2; nb++) acc[mb][nb] = (floatx4){0.f,0.f,0.f,0.f};

#define OSTAGE(bf, kk)                                                                  \
    {                                                                                   \
        int c = tid;                                                                    \
        async16(Ab + (size_t)(m_t + (c >> 2)) * D_MODEL + (kk) + ((((c & 3) ^ ((c >> 3) & 3))) * 8), \
                &la[bf][0][0][0] + c * 8);                                              \
        c = tid + 256;                                                                  \
        async16(Ab + (size_t)(m_t + (c >> 2)) * D_MODEL + (kk) + ((((c & 3) ^ ((c >> 3) & 3))) * 8), \
                &la[bf][0][0][0] + c * 8);                                              \
        c = tid;                                                                        \
        async16(Wb + (size_t)(n_t + (c >> 2)) * D_MODEL + (kk) + ((((c & 3) ^ ((c >> 3) & 3))) * 8), \
                &lb[bf][0][0][0] + c * 8);                                              \
    }

    OSTAGE(0, 0)

    const int swz = (laneM >> 1) & 3;
    for (int it = 0; it < 32; ++it) {
        const int bf = it & 1;
        __syncthreads();

        short8 af[4], bfv[2];
#pragma unroll
        for (int mb = 0; mb < 4; mb++) af[mb]  = *(const short8*)&la[bf][wm + mb*16 + laneM][quad ^ swz][0];
#pragma unroll
        for (int nb = 0; nb < 2; nb++) bfv[nb] = *(const short8*)&lb[bf][wn + nb*16 + laneM][quad ^ swz][0];

        if (it < 31) OSTAGE(bf ^ 1, (it + 1) * 32)

#pragma unroll
        for (int mb = 0; mb < 4; mb++)
#pragma unroll
            for (int nb = 0; nb < 2; nb++)
                acc[mb][nb] = __builtin_amdgcn_mfma_f32_16x16x32_bf16(af[mb], bfv[nb], acc[mb][nb], 0, 0, 0);
    }
#undef OSTAGE

#pragma unroll
    for (int nb = 0; nb < 2; nb++) {
        const int col = n_t + wn + nb*16 + laneM;
        const float bb = bias[col];
#pragma unroll
        for (int mb = 0; mb < 4; mb++) {
            const int row0 = m_t + wm + mb*16 + quad*4;
#pragma unroll
            for (int r = 0; r < 4; r++)
                out[(size_t)(row0 + r) * D_MODEL + col] = acc[mb][nb][r] + bb;
        }
    }
}

// ---------------------------------------------------------------- flash attention
// R7-exact interior (8 waves = 4 qg x 2 par, dbuf, in-register P frags, 0 LDS
// conflicts; R8/R9's 16-wave single-barrier-group variant produced 25M
// cross-SIMD LDS lockstep conflicts -> reverted). Two scheduling changes:
//  * 1D grid, bh = blockIdx&31: XCD = linear%8 = bh%8 -> all 16 q-blocks of a
//    bh colocate on one XCD; 4 bh x 512KB K+V = 2MB fits its 4MB L2.
//  * phase stagger po = (qi&3)*4: co-resident blocks hit different K/V phases
//    and different barrier rhythms (legal: max-free softmax is order-invariant).
__global__ __launch_bounds__(512, 4) void attn_kernel(const short* __restrict__ Qb,
                                                      const short* __restrict__ Kb,
                                                      const short* __restrict__ Vt,
                                                      short* __restrict__ Ob)
{
    const int bh = blockIdx.x & 31;
    const int qi = blockIdx.x >> 5;
    const int q0 = qi * 128;
    const int po = (qi & 3) * 4;                // phase stagger
    const int tid = threadIdx.x;
    const int wave = tid >> 6, lane = tid & 63;
    const int l31 = lane & 31;
    const bool hi = (lane >> 5) != 0;
    const int qg = wave & 3, par = wave >> 2;

    __shared__ short kt[2][2][8][64][8];    // [par][slot][d-octet][key][8]
    __shared__ short vtl[2][2][8][64][8];   // [par][slot][key-octet][d][8]

    const short* Kbase = Kb + (size_t)bh * SEQ * HDIM;
    const short* Vbase = Vt + (size_t)bh * HDIM * SEQ;

    // Q fragments (MFMA B operand: B[k=d][n=q], lane n = q)
    const short* Qp = Qb + ((size_t)bh * SEQ + q0 + qg*32 + l31) * HDIM + (hi ? 8 : 0);
    short8 qf[4];
#pragma unroll
    for (int ks = 0; ks < 4; ks++) qf[ks] = *(const short8*)(Qp + ks*16);

    floatx16 o0, o1;
#pragma unroll
    for (int r = 0; r < 16; r++) { o0[r] = 0.f; o1[r] = 0.f; }
    float rsum = 0.f;

    // stage key-blocks [kk,kk+64) -> [0][slot] and [kk+64,kk+128) -> [1][slot]
#define STAGE(slot, kk)                                                                   \
    {                                                                                     \
        const int c = tid;                                                                \
        async16(Kbase + (size_t)((kk) + (c & 63)) * HDIM + (c >> 6) * 8,                  \
                &kt[0][slot][0][0][0] + c * 8);                                           \
        async16(Kbase + (size_t)((kk) + 64 + (c & 63)) * HDIM + (c >> 6) * 8,             \
                &kt[1][slot][0][0][0] + c * 8);                                           \
        async16(Vbase + (size_t)(c & 63) * SEQ + (kk) + (c >> 6) * 8,                     \
                &vtl[0][slot][0][0][0] + c * 8);                                          \
        async16(Vbase + (size_t)(c & 63) * SEQ + (kk) + 64 + (c >> 6) * 8,                \
                &vtl[1][slot][0][0][0] + c * 8);                                          \
    }

    STAGE(0, po * 128)

    for (int i = 0; i < 16; ++i) {
        const int slot = i & 1;
        __syncthreads();                        // both parity tiles of phase i ready
        if (i < 15) STAGE(slot ^ 1, (((i + 1 + po) & 15)) * 128)

        // S^T: D[m=key][n=q]
        floatx16 s0, s1;
#pragma unroll
        for (int r = 0; r < 16; r++) { s0[r] = 0.f; s1[r] = 0.f; }
#pragma unroll
        for (int ks = 0; ks < 4; ks++) {
            const short8 a0 = *(const short8*)&kt[par][slot][2*ks + hi][l31][0];
            const short8 a1 = *(const short8*)&kt[par][slot][2*ks + hi][32 + l31][0];
            s0 = __builtin_amdgcn_mfma_f32_32x32x16_bf16(a0, qf[ks], s0, 0, 0, 0);
            s1 = __builtin_amdgcn_mfma_f32_32x32x16_bf16(a1, qf[ks], s1, 0, 0, 0);
        }

        // p = 2^s (raw v_exp_f32), per-lane rsum, pack adjacent-k pairs
        unsigned p[16];
#pragma unroll
        for (int i2 = 0; i2 < 8; i2++) {
            const float a0 = EXP2(s0[2*i2]), b0 = EXP2(s0[2*i2+1]);
            const float a1 = EXP2(s1[2*i2]), b1 = EXP2(s1[2*i2+1]);
            rsum += (a0 + b0) + (a1 + b1);
            p[i2]     = pk2(a0, b0);
            p[8 + i2] = pk2(a1, b1);
        }

        // build A-fragments: one shuffle serves both slots of a (pa,pb) pair
        unsigned fu[4][4];
#pragma unroll
        for (int g = 0; g < 4; g++) {
            const int base = (g >> 1) * 8 + (g & 1) * 4;  // 0,4,8,12
#pragma unroll
            for (int j = 0; j < 2; j++) {
                const unsigned pa = p[base + j], pb = p[base + j + 2];
                const unsigned pre = hi ? pa : pb;
                const unsigned sw = (unsigned)__shfl_xor((int)pre, 32, 64);
                fu[g][j]     = hi ? sw : pa;
                fu[g][j + 2] = hi ? pb : sw;
            }
        }

        // O += P V
#pragma unroll
        for (int ks = 0; ks < 4; ks++) {
            union { unsigned u[4]; short8 s; } pf;
            pf.u[0] = fu[ks][0]; pf.u[1] = fu[ks][1]; pf.u[2] = fu[ks][2]; pf.u[3] = fu[ks][3];
            const short8 v0 = *(const short8*)&vtl[par][slot][2*ks + hi][l31][0];
            const short8 v1 = *(const short8*)&vtl[par][slot][2*ks + hi][32 + l31][0];
            o0 = __builtin_amdgcn_mfma_f32_32x32x16_bf16(pf.s, v0, o0, 0, 0, 0);
            o1 = __builtin_amdgcn_mfma_f32_32x32x16_bf16(pf.s, v1, o1, 0, 0, 0);
        }
    }
#undef STAGE

    // own-wave key-half combine
    rsum += __shfl_xor(rsum, 32, 64);

    // parity merge via LDS (reuse staging buffers; all compute done after barrier)
    float* mO = (float*)&kt[0][0][0][0][0];     // [4][32][64]
    float* rS = (float*)&vtl[0][0][0][0][0];    // [4][32]
    __syncthreads();
    if (par == 1) {
#pragma unroll
        for (int r = 0; r < 16; r++) {
            const int qr = (r & 3) + 8 * (r >> 2) + (hi ? 4 : 0);
            mO[(qg*32 + qr)*64 + l31]      = o0[r];
            mO[(qg*32 + qr)*64 + 32 + l31] = o1[r];
        }
        if (!hi) rS[qg*32 + l31] = rsum;
    }
    __syncthreads();
    if (par == 0) {
        const float inv = 1.0f / (rsum + rS[qg*32 + l31]);  // lane l: q-row l31
        const int b = bh >> 4, h = bh & 15;
#pragma unroll
        for (int r = 0; r < 16; r++) {
            const int qr = (r & 3) + 8 * (r >> 2) + (hi ? 4 : 0);
            const float invr = __shfl(inv, qr, 64);
            const float v0 = o0[r] + mO[(qg*32 + qr)*64 + l31];
            const float v1 = o1[r] + mO[(qg*32 + qr)*64 + 32 + l31];
            const int seq = q0 + qg*32 + qr;
            short* dst = Ob + ((size_t)(b * SEQ + seq)) * D_MODEL + h * HDIM + l31;
            dst[0]  = f2bf(v0 * invr);
            dst[32] = f2bf(v1 * invr);
        }
    }
}

// ---------------------------------------------------------------- launch
extern "C" void kernel_launch(void* const* d_in, const int* in_sizes, int n_in,
                              void* d_out, int out_size, void* d_ws, size_t ws_size,
                              hipStream_t stream)
{
    const float* x  = (const float*)d_in[0];
    const float* Wq = (const float*)d_in[1];
    const float* bq = (const float*)d_in[2];
    const float* Wk = (const float*)d_in[3];
    const float* bk = (const float*)d_in[4];
    const float* Wv = (const float*)d_in[5];
    const float* bv = (const float*)d_in[6];
    const float* Wo = (const float*)d_in[7];
    const float* bo = (const float*)d_in[8];
    float* out = (float*)d_out;

    short* ws = (short*)d_ws;
    const size_t NX = (size_t)MTOT * D_MODEL;     // 4194304
    const size_t NW = (size_t)D_MODEL * D_MODEL;  // 1048576
    short* xb  = ws;
    short* wqb = xb  + NX;
    short* wkb = wqb + NW;
    short* wvb = wkb + NW;
    short* wob = wvb + NW;
    short* Qb  = wob + NW;
    short* Kb  = Qb  + NX;
    short* Vt  = Kb  + NX;   // V stored transposed directly by qkv_gemm
    short* Ob  = Vt  + NX;

    cast_all_kernel<<<dim3(4096), 256, 0, stream>>>(x, Wq, Wk, Wv, Wo, xb, wqb, wkb, wvb, wob);
    qkv_gemm_kernel<<<dim3(8, 32, 3), 256, 0, stream>>>(xb, wqb, wkb, wvb, bq, bk, bv, Qb, Kb, Vt);
    attn_kernel<<<dim3(512), 512, 0, stream>>>(Qb, Kb, Vt, Ob);
    out_gemm_kernel<<<dim3(16, 32), 256, 0, stream>>>(Ob, wob, bo, out);
}